// Round 1
// baseline (1316.391 us; speedup 1.0000x reference)
//
#include <hip/hip_runtime.h>

#define N 8192
#define NITER 20
#define TOLF 1e-10f

// ---------------- init: x=0, r=p=RHS, rtr0 = sum(RHS^2) ----------------
__global__ __launch_bounds__(256) void init_kernel(
    const float* __restrict__ RHS, float* __restrict__ x, float* __restrict__ r,
    float* __restrict__ p, float* __restrict__ rtr0) {
  int i = blockIdx.x * 256 + threadIdx.x;
  float v = RHS[i];
  x[i] = 0.0f;
  r[i] = v;
  p[i] = v;
  float val = v * v;
  for (int off = 32; off > 0; off >>= 1) val += __shfl_down(val, off, 64);
  __shared__ float bs[4];
  int wave = threadIdx.x >> 6, lane = threadIdx.x & 63;
  if (lane == 0) bs[wave] = val;
  __syncthreads();
  if (threadIdx.x == 0) atomicAdd(rtr0, bs[0] + bs[1] + bs[2] + bs[3]);
}

// ---------------- matvec: Ap = M @ p, pAp += p.Ap ----------------
// one wave per row, 4 rows per block, float4 coalesced loads
__global__ __launch_bounds__(256) void matvec_kernel(
    const float* __restrict__ M, const float* __restrict__ p,
    float* __restrict__ Ap, float* __restrict__ pAp) {
  int wave = threadIdx.x >> 6;
  int lane = threadIdx.x & 63;
  int row = blockIdx.x * 4 + wave;
  const float* Mr = M + (size_t)row * N;
  float sum = 0.0f;
#pragma unroll 4
  for (int c = lane * 4; c < N; c += 256) {
    float4 m  = *(const float4*)(Mr + c);
    float4 pv = *(const float4*)(p + c);
    sum += m.x * pv.x + m.y * pv.y + m.z * pv.z + m.w * pv.w;
  }
  for (int off = 32; off > 0; off >>= 1) sum += __shfl_down(sum, off, 64);
  __shared__ float bs[4];
  if (lane == 0) {
    Ap[row] = sum;
    bs[wave] = p[row] * sum;
  }
  __syncthreads();
  if (threadIdx.x == 0) atomicAdd(pAp, bs[0] + bs[1] + bs[2] + bs[3]);
}

// ---------------- update1: alpha; x += alpha p; r -= alpha Ap; rnorm = sum(rn^2)
__global__ __launch_bounds__(256) void update1_kernel(
    const float* __restrict__ Ap, const float* __restrict__ p,
    float* __restrict__ x, float* __restrict__ r,
    const float* __restrict__ rtr_i, const float* __restrict__ pAp_i,
    float* __restrict__ rnorm_i) {
  int i = blockIdx.x * 256 + threadIdx.x;
  float rtr = *rtr_i;
  bool active = rtr > TOLF;
  float val = 0.0f;
  if (active) {
    float alpha = rtr / *pAp_i;
    x[i] += alpha * p[i];
    float rn = r[i] - alpha * Ap[i];
    r[i] = rn;
    val = rn * rn;
  }
  for (int off = 32; off > 0; off >>= 1) val += __shfl_down(val, off, 64);
  __shared__ float bs[4];
  int wave = threadIdx.x >> 6, lane = threadIdx.x & 63;
  if (lane == 0) bs[wave] = val;
  __syncthreads();
  if (threadIdx.x == 0) atomicAdd(rnorm_i, bs[0] + bs[1] + bs[2] + bs[3]);
}

// ---------------- update2: beta; p = r + beta p; rtr[i+1] = active ? rnorm : rtr
__global__ __launch_bounds__(256) void update2_kernel(
    const float* __restrict__ r, float* __restrict__ p,
    const float* __restrict__ rtr_i, const float* __restrict__ rnorm_i,
    float* __restrict__ rtr_ip1) {
  int i = blockIdx.x * 256 + threadIdx.x;
  float rtr = *rtr_i;
  float rnorm = *rnorm_i;
  bool active = rtr > TOLF;
  if (active) {
    float beta = rnorm / rtr;
    p[i] = r[i] + beta * p[i];
  }
  if (i == 0) *rtr_ip1 = active ? rnorm : rtr;
}

extern "C" void kernel_launch(void* const* d_in, const int* in_sizes, int n_in,
                              void* d_out, int out_size, void* d_ws, size_t ws_size,
                              hipStream_t stream) {
  const float* M   = (const float*)d_in[1];
  const float* RHS = (const float*)d_in[2];
  float* out = (float*)d_out;

  float* ws = (float*)d_ws;
  float* Ap = ws;                 // N
  float* r  = ws + N;             // N
  float* p  = ws + 2 * N;         // N
  float* x  = ws + 3 * N;         // N
  float* sc = ws + 4 * N;         // scalars
  float* rtr   = sc;              // NITER+1
  float* pAp   = sc + (NITER + 1);// NITER
  float* rnorm = sc + (NITER + 1) + NITER; // NITER

  // zero the scalar region (re-poisoned to 0xAA before every timed call)
  hipMemsetAsync(sc, 0, (3 * NITER + 1) * sizeof(float), stream);

  init_kernel<<<N / 256, 256, 0, stream>>>(RHS, x, r, p, &rtr[0]);

  for (int i = 0; i < NITER; ++i) {
    matvec_kernel<<<N / 4, 256, 0, stream>>>(M, p, Ap, &pAp[i]);
    update1_kernel<<<N / 256, 256, 0, stream>>>(Ap, p, x, r, &rtr[i], &pAp[i], &rnorm[i]);
    update2_kernel<<<N / 256, 256, 0, stream>>>(r, p, &rtr[i], &rnorm[i], &rtr[i + 1]);
  }

  hipMemcpyAsync(out, x, N * sizeof(float), hipMemcpyDeviceToDevice, stream);
}